// Round 1
// baseline (477.113 us; speedup 1.0000x reference)
//
#include <hip/hip_runtime.h>
#include <stdint.h>

// Problem constants (fixed by the reference): x is (128,1,512,512) fp32, k=2048.
#define B        128
#define ROW_N    262144                 // 512*512 elements per row
#define NBUCKET  4096                   // 12-bit key buckets
#define KSHIFT   19                     // (bits & 0x7FFFFFFF) >> 19 -> 0..4095
#define CAND_MAX 4096                   // candidate slots per row (expected ~700)
#define CHUNK    32768                  // floats per block in the streaming passes
#define CHUNKS_PER_ROW (ROW_N / CHUNK)  // 8
#define THREADS  256
#define V4_PER_THREAD (CHUNK / 4 / THREADS)  // 32 float4 per thread

// workspace layout (bytes)
#define OFF_HIST 0
#define SZ_HIST  (B * NBUCKET * 4)          // 2 MiB
#define OFF_CNT  (OFF_HIST + SZ_HIST)       // per-row candidate counters (B u32)
#define OFF_BKT  (OFF_CNT + 512)            // per-row threshold bucket (B int)
#define OFF_NEED (OFF_BKT + 512)            // per-row remaining count (B int)
#define OFF_CAND (OFF_NEED + 512)           // B * CAND_MAX * uint2

// ---------------- pass 1: per-row 12-bit histogram of |x| bits ----------------
__global__ __launch_bounds__(THREADS) void hist_kernel(const float* __restrict__ x,
                                                       unsigned* __restrict__ hist) {
    __shared__ unsigned h[NBUCKET];   // 16 KiB
    const int t = threadIdx.x;
    for (int i = t; i < NBUCKET; i += THREADS) h[i] = 0;
    __syncthreads();

    const int row = blockIdx.y;
    const float4* xr = (const float4*)(x + (size_t)row * ROW_N);
    const int base4 = blockIdx.x * (CHUNK / 4);
#pragma unroll
    for (int i = 0; i < V4_PER_THREAD; ++i) {
        float4 v = xr[base4 + i * THREADS + t];
        atomicAdd(&h[(__float_as_uint(v.x) & 0x7FFFFFFFu) >> KSHIFT], 1u);
        atomicAdd(&h[(__float_as_uint(v.y) & 0x7FFFFFFFu) >> KSHIFT], 1u);
        atomicAdd(&h[(__float_as_uint(v.z) & 0x7FFFFFFFu) >> KSHIFT], 1u);
        atomicAdd(&h[(__float_as_uint(v.w) & 0x7FFFFFFFu) >> KSHIFT], 1u);
    }
    __syncthreads();

    unsigned* gh = hist + (size_t)row * NBUCKET;
    for (int i = t; i < NBUCKET; i += THREADS) {
        unsigned c = h[i];
        if (c) atomicAdd(&gh[i], c);
    }
}

// -------- pass 2: per-row suffix scan from the top bucket; find threshold ------
__global__ __launch_bounds__(THREADS) void select_kernel(const unsigned* __restrict__ hist,
                                                         const int* __restrict__ topk,
                                                         int* __restrict__ row_bucket,
                                                         int* __restrict__ row_need) {
    const int row = blockIdx.x;
    const int t = threadIdx.x;
    const unsigned K = (unsigned)(*topk);
    const unsigned* gh = hist + (size_t)row * NBUCKET;

    __shared__ unsigned partial[THREADS];
    __shared__ unsigned excl[THREADS];
    const int PER = NBUCKET / THREADS;  // 16 buckets per thread, descending order
    unsigned s = 0;
#pragma unroll
    for (int i = 0; i < PER; ++i) s += gh[NBUCKET - 1 - (t * PER + i)];
    partial[t] = s;
    __syncthreads();
    if (t == 0) {
        unsigned c = 0;
        for (int i = 0; i < THREADS; ++i) { excl[i] = c; c += partial[i]; }
    }
    __syncthreads();

    unsigned cum = excl[t];
#pragma unroll
    for (int i = 0; i < PER; ++i) {
        const int bucket = NBUCKET - 1 - (t * PER + i);
        const unsigned c = gh[bucket];
        if (cum < K && cum + c >= K) {   // unique crossing thread/iteration
            row_bucket[row] = bucket;
            row_need[row]   = (int)(K - cum);
        }
        cum += c;
    }
}

// ----- pass 3: stream output; collect exact-bucket candidates for tie-break ----
__global__ __launch_bounds__(THREADS) void output_kernel(const float* __restrict__ x,
                                                         float* __restrict__ out,
                                                         const int* __restrict__ row_bucket,
                                                         unsigned* __restrict__ cand_count,
                                                         uint2* __restrict__ cand) {
    const int row = blockIdx.y;
    const int b = row_bucket[row];
    const size_t rowbase = (size_t)row * ROW_N;
    const float4* xr = (const float4*)(x + rowbase);
    float4* outr = (float4*)(out + rowbase);
    const int base4 = blockIdx.x * (CHUNK / 4);
    const int t = threadIdx.x;
#pragma unroll
    for (int i = 0; i < V4_PER_THREAD; ++i) {
        const int i4 = base4 + i * THREADS + t;
        float4 v = xr[i4];
        float4 o;
        float* vp = &v.x;
        float* op = &o.x;
#pragma unroll
        for (int c = 0; c < 4; ++c) {
            const unsigned ubits = __float_as_uint(vp[c]);
            const int key = (int)((ubits & 0x7FFFFFFFu) >> KSHIFT);
            if (key > b) {
                op[c] = vp[c];
            } else {
                op[c] = 0.0f;
                if (key == b) {
                    const unsigned pos = atomicAdd(&cand_count[row], 1u);
                    if (pos < CAND_MAX)
                        cand[(size_t)row * CAND_MAX + pos] =
                            make_uint2((unsigned)(i4 * 4 + c), ubits);
                }
            }
        }
        outr[i4] = o;
    }
}

// ---- pass 4: exact top-`need` among candidates (desc |x|, asc index on tie) ---
__global__ __launch_bounds__(THREADS) void fixup_kernel(float* __restrict__ out,
                                                        const int* __restrict__ row_need,
                                                        const unsigned* __restrict__ cand_count,
                                                        const uint2* __restrict__ cand) {
    const int row = blockIdx.x;
    const int t = threadIdx.x;
    unsigned cc = cand_count[row];
    const int c = (int)(cc < (unsigned)CAND_MAX ? cc : (unsigned)CAND_MAX);
    const int need = row_need[row];

    __shared__ unsigned sidx[CAND_MAX];   // 16 KiB
    __shared__ unsigned sbits[CAND_MAX];  // 16 KiB
    const uint2* rc = cand + (size_t)row * CAND_MAX;
    for (int i = t; i < c; i += THREADS) {
        uint2 e = rc[i];
        sidx[i] = e.x;
        sbits[i] = e.y;
    }
    __syncthreads();

    const size_t rowbase = (size_t)row * ROW_N;
    for (int i = t; i < c; i += THREADS) {
        const unsigned bits = sbits[i];
        const unsigned idx = sidx[i];
        const uint64_t key =
            ((uint64_t)(bits & 0x7FFFFFFFu) << 32) | (uint64_t)(~idx);
        int rank = 0;
        for (int j = 0; j < c; ++j) {
            const uint64_t kj =
                ((uint64_t)(sbits[j] & 0x7FFFFFFFu) << 32) | (uint64_t)(~sidx[j]);
            rank += (kj > key) ? 1 : 0;
        }
        if (rank < need) out[rowbase + idx] = __uint_as_float(bits);
    }
}

extern "C" void kernel_launch(void* const* d_in, const int* in_sizes, int n_in,
                              void* d_out, int out_size, void* d_ws, size_t ws_size,
                              hipStream_t stream) {
    const float* x = (const float*)d_in[0];
    const int* topk = (const int*)d_in[1];
    float* out = (float*)d_out;
    char* ws = (char*)d_ws;

    unsigned* hist       = (unsigned*)(ws + OFF_HIST);
    unsigned* cand_count = (unsigned*)(ws + OFF_CNT);
    int* row_bucket      = (int*)(ws + OFF_BKT);
    int* row_need        = (int*)(ws + OFF_NEED);
    uint2* cand          = (uint2*)(ws + OFF_CAND);

    // zero histograms + candidate counters (ws is re-poisoned to 0xAA each run)
    hipMemsetAsync(ws, 0, SZ_HIST + 512, stream);

    dim3 grid_stream(CHUNKS_PER_ROW, B);  // 8 x 128 = 1024 blocks
    hist_kernel<<<grid_stream, THREADS, 0, stream>>>(x, hist);
    select_kernel<<<B, THREADS, 0, stream>>>(hist, topk, row_bucket, row_need);
    output_kernel<<<grid_stream, THREADS, 0, stream>>>(x, out, row_bucket, cand_count, cand);
    fixup_kernel<<<B, THREADS, 0, stream>>>(out, row_need, cand_count, cand);
}